// Round 2
// baseline (572.846 us; speedup 1.0000x reference)
//
#include <hip/hip_runtime.h>
#include <stdint.h>

// ---------------- constants ----------------
#define SEQ   2048
#define NH    16
#define DIMM  2048
#define QLR   768
#define KVLR  512
#define DN    128
#define DR    64
#define DV    128
#define QKH   192           // DN + DR
#define KVPAD 640           // 576 padded to multiple of 128
#define SCALE_F 0.07216878364870323f   // 192^-0.5
#define LAM_INIT 0.5560582f            // 0.8 - 0.6*exp(-0.9)
#define C1F      0.4439418f            // 1 - LAM_INIT

// ---------------- types ----------------
typedef __attribute__((ext_vector_type(8))) uint16_t u16x8;
typedef __attribute__((ext_vector_type(8))) __bf16   bf16x8;
typedef __attribute__((ext_vector_type(4))) float    f32x4;

#define MFMA16(a,b,c) __builtin_amdgcn_mfma_f32_16x16x32_bf16((a),(b),(c),0,0,0)

__device__ __forceinline__ uint16_t f2bf(float f){ uint32_t x; __builtin_memcpy(&x,&f,4); return (uint16_t)((x + 0x7FFFu + ((x>>16)&1u))>>16); }
__device__ __forceinline__ bf16x8 ldfrag(const uint16_t* p){ return __builtin_bit_cast(bf16x8, *(const u16x8*)p); }
__device__ __forceinline__ void gload_lds16(const uint16_t* g, uint16_t* l){
  __builtin_amdgcn_global_load_lds((const __attribute__((address_space(1))) void*)g,
                                   (__attribute__((address_space(3))) void*)l, 16, 0, 0);
}
__device__ __forceinline__ void stor(uint16_t* p, float v){ *p = f2bf(v); }
__device__ __forceinline__ void stor(float* p, float v){ *p = v; }

// ---------------- f32 -> bf16 converters ----------------
__global__ void cvt(const float* __restrict__ in, uint16_t* __restrict__ outp){
  int i = (blockIdx.x*256 + threadIdx.x)*8;
  float4 a = *(const float4*)(in + i);
  float4 b = *(const float4*)(in + i + 4);
  u16x8 r;
  r[0]=f2bf(a.x); r[1]=f2bf(a.y); r[2]=f2bf(a.z); r[3]=f2bf(a.w);
  r[4]=f2bf(b.x); r[5]=f2bf(b.y); r[6]=f2bf(b.z); r[7]=f2bf(b.w);
  *(u16x8*)(outp + i) = r;
}

// wkv_a f32 [576][2048] -> bf16 [640][2048] zero-padded
__global__ void pad_wkva(const float* __restrict__ in, uint16_t* __restrict__ outp){
  int idx = blockIdx.x*256 + threadIdx.x;          // KVPAD*DIMM
  int n = idx >> 11;
  outp[idx] = (n < 576) ? f2bf(in[idx]) : (uint16_t)0;
}

// ---------------- GEMM: C[M][N] = A[M][K] (lda) * B[N][K]^T, bf16 in, f32 acc ----
// 128x128 tile, 4 waves (2x2 of 64x64), BK=32, global_load_lds staging.
template <typename OT>
__global__ __launch_bounds__(256) void gemm_bt(const uint16_t* __restrict__ A, int lda,
                                               const uint16_t* __restrict__ B,
                                               OT* __restrict__ C, int ldc, int K)
{
  __shared__ __align__(16) uint16_t As[128*32];
  __shared__ __align__(16) uint16_t Bs[128*32];
  const int tid  = threadIdx.x;
  const int wid  = tid >> 6;
  const int lane = tid & 63;
  const int wr   = (wid >> 1) * 64;
  const int wc   = (wid & 1) * 64;
  const int srow = lane >> 2;          // staging row within 16-row chunk
  const int scol = (lane & 3) * 8;     // staging col (elements)
  const uint16_t* Abase = A + (size_t)(blockIdx.x * 128) * lda;
  const uint16_t* Bbase = B + (size_t)(blockIdx.y * 128) * K;
  f32x4 acc[4][4] = {};
  for (int k0 = 0; k0 < K; k0 += 32) {
    __syncthreads();
#pragma unroll
    for (int c = 0; c < 2; ++c) {
      int r = (wid*2 + c)*16 + srow;
      gload_lds16(Abase + (size_t)r*lda + k0 + scol, &As[(wid*2 + c)*512]);
      gload_lds16(Bbase + (size_t)r*K   + k0 + scol, &Bs[(wid*2 + c)*512]);
    }
    __syncthreads();
    bf16x8 af[4], bfr[4];
#pragma unroll
    for (int m = 0; m < 4; ++m)
      af[m] = ldfrag(&As[(wr + m*16 + (lane&15))*32 + ((lane>>4)*8)]);
#pragma unroll
    for (int n = 0; n < 4; ++n)
      bfr[n] = ldfrag(&Bs[(wc + n*16 + (lane&15))*32 + ((lane>>4)*8)]);
#pragma unroll
    for (int m = 0; m < 4; ++m)
#pragma unroll
      for (int n = 0; n < 4; ++n)
        acc[m][n] = MFMA16(af[m], bfr[n], acc[m][n]);
  }
  // C/D layout: col = lane&15, row = (lane>>4)*4 + reg  [measured m89]
  const int rbase = blockIdx.x*128 + wr + ((lane>>4)<<2);
  const int cbase = blockIdx.y*128 + wc + (lane&15);
#pragma unroll
  for (int m = 0; m < 4; ++m)
#pragma unroll
    for (int n = 0; n < 4; ++n)
#pragma unroll
      for (int r = 0; r < 4; ++r)
        stor(&C[(size_t)(rbase + m*16 + r)*ldc + cbase + n*16], acc[m][n][r]);
}

// ---------------- small kernels ----------------
__global__ void lam_kernel(const float* lqn, const float* lqr,
                           const float* lkn, const float* lkr, float* outp){
  if (threadIdx.x == 0 && blockIdx.x == 0) {
    float d1 = 0.f, d2 = 0.f;
    for (int i = 0; i < DN; ++i) d1 += lqn[i] * lkn[i];
    for (int i = 0; i < DR; ++i) d2 += lqr[i] * lkr[i];
    outp[0] = __expf(d1) - __expf(d2) + LAM_INIT;
  }
}

__global__ void rope_q(uint16_t* __restrict__ q, const float* __restrict__ cs,
                       const float* __restrict__ sn){
  int idx = blockIdx.x*256 + threadIdx.x;          // SEQ*NH*32
  int j = idx & 31, hh = (idx>>5) & 15, s = idx >> 9;
  uint16_t* p = q + (size_t)s*(NH*QKH) + hh*QKH + DN + 2*j;
  float xr = (float)__builtin_bit_cast(__bf16, p[0]);
  float xi = (float)__builtin_bit_cast(__bf16, p[1]);
  float c = cs[s*32+j], si = sn[s*32+j];
  p[0] = f2bf(xr*c - xi*si);
  p[1] = f2bf(xr*si + xi*c);
}

// k_full[h][t][192] = { kvb[t][h*256+d] (d<128) ; rope(k_pe)[t][d-128] }
__global__ void mat_k(const uint16_t* __restrict__ kvb, const uint16_t* __restrict__ kvf,
                      const float* __restrict__ cs, const float* __restrict__ sn,
                      uint16_t* __restrict__ kfull){
  int idx = blockIdx.x*256 + threadIdx.x;          // NH*SEQ*QKH
  int d = idx % QKH; int th = idx / QKH; int t = th & 2047; int hh = th >> 11;
  uint16_t val;
  if (d < DN) {
    val = kvb[(size_t)t*4096 + hh*256 + d];
  } else {
    int dd = d - DN, j = dd >> 1;
    float xr = (float)__builtin_bit_cast(__bf16, kvf[(size_t)t*KVPAD + KVLR + 2*j]);
    float xi = (float)__builtin_bit_cast(__bf16, kvf[(size_t)t*KVPAD + KVLR + 2*j + 1]);
    float c = cs[t*32+j], si = sn[t*32+j];
    val = f2bf((dd & 1) ? (xr*si + xi*c) : (xr*c - xi*si));
  }
  kfull[idx] = val;
}

// v_t[h][d][t] = kvb[t][h*256+128+d]
__global__ void mat_v(const uint16_t* __restrict__ kvb, uint16_t* __restrict__ vtp){
  int idx = blockIdx.x*256 + threadIdx.x;          // NH*DV*SEQ
  int t = idx & 2047, d = (idx>>11) & 127, hh = idx >> 18;
  vtp[idx] = kvb[(size_t)t*4096 + hh*256 + DN + d];
}

// ---------------- attention ----------------
// grid (32 qblocks, 16 heads), 256 thr. Wave w owns 16 q-rows. t-tiles of 32.
__device__ __forceinline__ void proc_set(f32x4 s[2], float m[4], float l[4], f32x4 O[8],
                                         uint16_t* pl, int qrow0, int t0, int subrow, int l15)
{
#pragma unroll
  for (int half = 0; half < 2; ++half)
#pragma unroll
    for (int r = 0; r < 4; ++r) {
      float v = s[half][r] * SCALE_F;
      v = fminf(fmaxf(v, -100.f), 100.f);
      if (t0 + half*16 + l15 > qrow0 + subrow + r) v = -1e30f;   // causal
      s[half][r] = v;
    }
  float corr[4];
#pragma unroll
  for (int r = 0; r < 4; ++r) {
    float tm = fmaxf(s[0][r], s[1][r]);
#pragma unroll
    for (int off = 1; off < 16; off <<= 1) tm = fmaxf(tm, __shfl_xor(tm, off, 64));
    float mn = fmaxf(m[r], tm);
    corr[r] = __expf(m[r] - mn);
    m[r] = mn;
  }
#pragma unroll
  for (int r = 0; r < 4; ++r) {
    s[0][r] = __expf(s[0][r] - m[r]);
    s[1][r] = __expf(s[1][r] - m[r]);
    float rs = s[0][r] + s[1][r];
#pragma unroll
    for (int off = 1; off < 16; off <<= 1) rs += __shfl_xor(rs, off, 64);
    l[r] = l[r]*corr[r] + rs;
  }
#pragma unroll
  for (int n = 0; n < 8; ++n)
#pragma unroll
    for (int r = 0; r < 4; ++r) O[n][r] *= corr[r];
#pragma unroll
  for (int half = 0; half < 2; ++half)
#pragma unroll
    for (int r = 0; r < 4; ++r)
      pl[(subrow + r)*32 + half*16 + l15] = f2bf(s[half][r]);
}

__global__ __launch_bounds__(256) void attn_kernel(
    const uint16_t* __restrict__ q,     // [SEQ][NH*QKH]
    const uint16_t* __restrict__ kf,    // [NH][SEQ][QKH]
    const uint16_t* __restrict__ vt,    // [NH][DV][SEQ]
    const float* __restrict__ lamp,
    uint16_t* __restrict__ o)           // [SEQ][NH*DV]
{
  __shared__ __align__(16) uint16_t P_lds[4][2][16*32];
  const int h  = blockIdx.y;
  const int qb = blockIdx.x;
  const int wid  = threadIdx.x >> 6;
  const int lane = threadIdx.x & 63;
  const int l15 = lane & 15;
  const int lhi = lane >> 4;
  const int subrow = lhi * 4;
  const int qrow0 = qb*64 + wid*16;
  const float lam = lamp[0];

  bf16x8 qf[6];
  {
    const uint16_t* qbase = q + (size_t)(qrow0 + l15)*(NH*QKH) + h*QKH + lhi*8;
#pragma unroll
    for (int kb = 0; kb < 6; ++kb) qf[kb] = ldfrag(qbase + kb*32);
  }
  f32x4 O1[8] = {}, O2[8] = {};
  float m1[4], m2[4], l1[4], l2[4];
#pragma unroll
  for (int r = 0; r < 4; ++r) { m1[r] = m2[r] = -1e30f; l1[r] = l2[r] = 0.f; }

  const uint16_t* kbase = kf + (size_t)h*SEQ*QKH;
  const uint16_t* vbase = vt + (size_t)h*DV*SEQ;
  const int tmaxw = qrow0 + 15;
  const int tend  = qb*64 + 64;
  for (int t0 = 0; t0 < tend; t0 += 32) {
    const bool active = (t0 <= tmaxw);
    if (active) {
      f32x4 s1[2] = {}, s2[2] = {};
#pragma unroll
      for (int half = 0; half < 2; ++half) {
        const uint16_t* kp = kbase + (size_t)(t0 + half*16 + l15)*QKH + lhi*8;
#pragma unroll
        for (int kb = 0; kb < 3; ++kb) s1[half] = MFMA16(qf[kb], ldfrag(kp + kb*32), s1[half]);
#pragma unroll
        for (int kb = 3; kb < 6; ++kb) s2[half] = MFMA16(qf[kb], ldfrag(kp + kb*32), s2[half]);
      }
      proc_set(s1, m1, l1, O1, &P_lds[wid][0][0], qrow0, t0, subrow, l15);
      proc_set(s2, m2, l2, O2, &P_lds[wid][1][0], qrow0, t0, subrow, l15);
    }
    __syncthreads();
    if (active) {
#pragma unroll
      for (int set = 0; set < 2; ++set) {
        bf16x8 pf = ldfrag(&P_lds[wid][set][l15*32 + lhi*8]);
        f32x4* O = set ? O2 : O1;
#pragma unroll
        for (int n = 0; n < 8; ++n) {
          bf16x8 vf = ldfrag(vbase + (size_t)(n*16 + l15)*SEQ + t0 + lhi*8);
          O[n] = MFMA16(pf, vf, O[n]);
        }
      }
    }
    __syncthreads();
  }
  // epilogue: (O1/l1 - lam*O2/l2) * (1-lambda_init)
#pragma unroll
  for (int r = 0; r < 4; ++r) {
    float inv1 = 1.f / l1[r], inv2 = lam / l2[r];
#pragma unroll
    for (int n = 0; n < 8; ++n) {
      float val = (O1[n][r]*inv1 - O2[n][r]*inv2) * C1F;
      o[(size_t)(qrow0 + subrow + r)*(NH*DV) + h*DV + n*16 + l15] = f2bf(val);
    }
  }
}

// ---------------- launch ----------------
extern "C" void kernel_launch(void* const* d_in, const int* in_sizes, int n_in,
                              void* d_out, int out_size, void* d_ws, size_t ws_size,
                              hipStream_t stream)
{
  const float* x     = (const float*)d_in[0];
  const float* wq_a  = (const float*)d_in[1];
  const float* wq_b  = (const float*)d_in[2];
  const float* wkv_a = (const float*)d_in[3];
  const float* wkv_b = (const float*)d_in[4];
  const float* wo    = (const float*)d_in[5];
  const float* lqn   = (const float*)d_in[6];
  const float* lqr   = (const float*)d_in[7];
  const float* lkn   = (const float*)d_in[8];
  const float* lkr   = (const float*)d_in[9];
  const float* fcos  = (const float*)d_in[10];
  const float* fsin  = (const float*)d_in[11];

  char* ws = (char*)d_ws;
  size_t off = 0;
  float*    lam    = (float*)(ws + off);  off += 256;
  uint16_t* xb     = (uint16_t*)(ws + off); off += (size_t)DIMM*DIMM*2;        // 8,388,608
  uint16_t* wqab   = (uint16_t*)(ws + off); off += (size_t)QLR*DIMM*2;         // 3,145,728
  uint16_t* wqbb   = (uint16_t*)(ws + off); off += (size_t)NH*QKH*QLR*2;       // 4,718,592
  uint16_t* wkvap  = (uint16_t*)(ws + off); off += (size_t)KVPAD*DIMM*2;       // 2,621,440
  uint16_t* wkvbb  = (uint16_t*)(ws + off); off += (size_t)4096*KVLR*2;        // 4,194,304
  uint16_t* wob    = (uint16_t*)(ws + off); off += (size_t)DIMM*DIMM*2;        // 8,388,608
  uint16_t* qlat   = (uint16_t*)(ws + off); off += (size_t)SEQ*QLR*2;          // 3,145,728
  uint16_t* qbuf   = (uint16_t*)(ws + off); off += (size_t)SEQ*NH*QKH*2;       // 12,582,912
  uint16_t* kvfull = (uint16_t*)(ws + off); off += (size_t)SEQ*KVPAD*2;        // 2,621,440
  uint16_t* kvb    = (uint16_t*)(ws + off); off += (size_t)SEQ*4096*2;         // 16,777,216
  uint16_t* kfull  = (uint16_t*)(ws + off); off += (size_t)NH*SEQ*QKH*2;       // 12,582,912
  uint16_t* vtb    = (uint16_t*)(ws + off); off += (size_t)NH*DV*SEQ*2;        // 8,388,608
  uint16_t* attn   = (uint16_t*)(ws + off); off += (size_t)SEQ*NH*DV*2;        // 8,388,608

  lam_kernel<<<1, 64, 0, stream>>>(lqn, lqr, lkn, lkr, lam);
  cvt<<<2048, 256, 0, stream>>>(x, xb);          // 2048*2048
  cvt<<< 768, 256, 0, stream>>>(wq_a, wqab);     // 768*2048
  cvt<<<1152, 256, 0, stream>>>(wq_b, wqbb);     // 3072*768
  cvt<<<1024, 256, 0, stream>>>(wkv_b, wkvbb);   // 4096*512
  cvt<<<2048, 256, 0, stream>>>(wo, wob);        // 2048*2048
  pad_wkva<<<5120, 256, 0, stream>>>(wkv_a, wkvap);

  // q_lat = x @ wq_a^T
  gemm_bt<<<dim3(16, 6), 256, 0, stream>>>(xb, DIMM, wqab, qlat, QLR, DIMM);
  // q = q_lat @ wq_b^T
  gemm_bt<<<dim3(16, 24), 256, 0, stream>>>(qlat, QLR, wqbb, qbuf, NH*QKH, QLR);
  rope_q<<<4096, 256, 0, stream>>>(qbuf, fcos, fsin);
  // kv_full = x @ wkv_a_pad^T
  gemm_bt<<<dim3(16, 5), 256, 0, stream>>>(xb, DIMM, wkvap, kvfull, KVPAD, DIMM);
  // kvb = kv @ wkv_b^T   (kv = first 512 cols of kvfull, lda=640)
  gemm_bt<<<dim3(16, 32), 256, 0, stream>>>(kvfull, KVPAD, wkvbb, kvb, 4096, KVLR);
  mat_k<<<24576, 256, 0, stream>>>(kvb, kvfull, fcos, fsin, kfull);
  mat_v<<<16384, 256, 0, stream>>>(kvb, vtb);
  attn_kernel<<<dim3(32, 16), 256, 0, stream>>>(qbuf, kfull, vtb, lam, attn);
  // out = attn_out @ wo^T  (f32 output)
  gemm_bt<<<dim3(16, 16), 256, 0, stream>>>(attn, NH*DV, wob, (float*)d_out, DIMM, DIMM);
}

// Round 3
// 385.624 us; speedup vs baseline: 1.4855x; 1.4855x over previous
//
#include <hip/hip_runtime.h>
#include <stdint.h>

// ---------------- constants ----------------
#define SEQ   2048
#define NH    16
#define DIMM  2048
#define QLR   768
#define KVLR  512
#define DN    128
#define DR    64
#define DV    128
#define QKH   192           // DN + DR
#define KVPAD 640           // 576 padded to multiple of 128
#define SCALE_F 0.07216878364870323f   // 192^-0.5
#define LAM_INIT 0.5560582f            // 0.8 - 0.6*exp(-0.9)
#define C1F      0.4439418f            // 1 - LAM_INIT
#define PSTR  36            // P_lds row stride (elements) — conflict-breaking pad

// ---------------- types ----------------
typedef __attribute__((ext_vector_type(8))) uint16_t u16x8;
typedef __attribute__((ext_vector_type(8))) __bf16   bf16x8;
typedef __attribute__((ext_vector_type(4))) float    f32x4;

#define MFMA16(a,b,c) __builtin_amdgcn_mfma_f32_16x16x32_bf16((a),(b),(c),0,0,0)

__device__ __forceinline__ uint16_t f2bf(float f){ uint32_t x; __builtin_memcpy(&x,&f,4); return (uint16_t)((x + 0x7FFFu + ((x>>16)&1u))>>16); }
__device__ __forceinline__ bf16x8 ldfrag(const uint16_t* p){ return __builtin_bit_cast(bf16x8, *(const u16x8*)p); }
__device__ __forceinline__ void gload_lds16(const uint16_t* g, uint16_t* l){
  __builtin_amdgcn_global_load_lds((const __attribute__((address_space(1))) void*)g,
                                   (__attribute__((address_space(3))) void*)l, 16, 0, 0);
}
__device__ __forceinline__ void stor(uint16_t* p, float v){ *p = f2bf(v); }
__device__ __forceinline__ void stor(float* p, float v){ *p = v; }

// ---------------- f32 -> bf16 converters ----------------
__global__ void cvt(const float* __restrict__ in, uint16_t* __restrict__ outp){
  int i = (blockIdx.x*256 + threadIdx.x)*8;
  float4 a = *(const float4*)(in + i);
  float4 b = *(const float4*)(in + i + 4);
  u16x8 r;
  r[0]=f2bf(a.x); r[1]=f2bf(a.y); r[2]=f2bf(a.z); r[3]=f2bf(a.w);
  r[4]=f2bf(b.x); r[5]=f2bf(b.y); r[6]=f2bf(b.z); r[7]=f2bf(b.w);
  *(u16x8*)(outp + i) = r;
}

// wkv_a f32 [576][2048] -> bf16 [640][2048] zero-padded
__global__ void pad_wkva(const float* __restrict__ in, uint16_t* __restrict__ outp){
  int idx = blockIdx.x*256 + threadIdx.x;          // KVPAD*DIMM
  int n = idx >> 11;
  outp[idx] = (n < 576) ? f2bf(in[idx]) : (uint16_t)0;
}

// ---------------- GEMM: C[M][N] = A[M][K] (lda) * B[N][K]^T, bf16 in, f32 acc ----
// 128x128 tile, 4 waves (2x2 of 64x64), BK=32, global_load_lds staging.
template <typename OT>
__global__ __launch_bounds__(256) void gemm_bt(const uint16_t* __restrict__ A, int lda,
                                               const uint16_t* __restrict__ B,
                                               OT* __restrict__ C, int ldc, int K)
{
  __shared__ __align__(16) uint16_t As[128*32];
  __shared__ __align__(16) uint16_t Bs[128*32];
  const int tid  = threadIdx.x;
  const int wid  = tid >> 6;
  const int lane = tid & 63;
  const int wr   = (wid >> 1) * 64;
  const int wc   = (wid & 1) * 64;
  const int srow = lane >> 2;          // staging row within 16-row chunk
  const int scol = (lane & 3) * 8;     // staging col (elements)
  const uint16_t* Abase = A + (size_t)(blockIdx.x * 128) * lda;
  const uint16_t* Bbase = B + (size_t)(blockIdx.y * 128) * K;
  f32x4 acc[4][4] = {};
  for (int k0 = 0; k0 < K; k0 += 32) {
    __syncthreads();
#pragma unroll
    for (int c = 0; c < 2; ++c) {
      int r = (wid*2 + c)*16 + srow;
      gload_lds16(Abase + (size_t)r*lda + k0 + scol, &As[(wid*2 + c)*512]);
      gload_lds16(Bbase + (size_t)r*K   + k0 + scol, &Bs[(wid*2 + c)*512]);
    }
    __syncthreads();
    bf16x8 af[4], bfr[4];
#pragma unroll
    for (int m = 0; m < 4; ++m)
      af[m] = ldfrag(&As[(wr + m*16 + (lane&15))*32 + ((lane>>4)*8)]);
#pragma unroll
    for (int n = 0; n < 4; ++n)
      bfr[n] = ldfrag(&Bs[(wc + n*16 + (lane&15))*32 + ((lane>>4)*8)]);
#pragma unroll
    for (int m = 0; m < 4; ++m)
#pragma unroll
      for (int n = 0; n < 4; ++n)
        acc[m][n] = MFMA16(af[m], bfr[n], acc[m][n]);
  }
  // C/D layout: col = lane&15, row = (lane>>4)*4 + reg  [measured m89]
  const int rbase = blockIdx.x*128 + wr + ((lane>>4)<<2);
  const int cbase = blockIdx.y*128 + wc + (lane&15);
#pragma unroll
  for (int m = 0; m < 4; ++m)
#pragma unroll
    for (int n = 0; n < 4; ++n)
#pragma unroll
      for (int r = 0; r < 4; ++r)
        stor(&C[(size_t)(rbase + m*16 + r)*ldc + cbase + n*16], acc[m][n][r]);
}

// ---------------- small kernels ----------------
__global__ void lam_kernel(const float* lqn, const float* lqr,
                           const float* lkn, const float* lkr, float* outp){
  if (threadIdx.x == 0 && blockIdx.x == 0) {
    float d1 = 0.f, d2 = 0.f;
    for (int i = 0; i < DN; ++i) d1 += lqn[i] * lkn[i];
    for (int i = 0; i < DR; ++i) d2 += lqr[i] * lkr[i];
    outp[0] = __expf(d1) - __expf(d2) + LAM_INIT;
  }
}

__global__ void rope_q(uint16_t* __restrict__ q, const float* __restrict__ cs,
                       const float* __restrict__ sn){
  int idx = blockIdx.x*256 + threadIdx.x;          // SEQ*NH*32
  int j = idx & 31, hh = (idx>>5) & 15, s = idx >> 9;
  uint16_t* p = q + (size_t)s*(NH*QKH) + hh*QKH + DN + 2*j;
  float xr = (float)__builtin_bit_cast(__bf16, p[0]);
  float xi = (float)__builtin_bit_cast(__bf16, p[1]);
  float c = cs[s*32+j], si = sn[s*32+j];
  p[0] = f2bf(xr*c - xi*si);
  p[1] = f2bf(xr*si + xi*c);
}

// k_full[h][t][192] = { kvb[t][h*256+d] (d<128) ; rope(k_pe)[t][d-128] }
__global__ void mat_k(const uint16_t* __restrict__ kvb, const uint16_t* __restrict__ kvf,
                      const float* __restrict__ cs, const float* __restrict__ sn,
                      uint16_t* __restrict__ kfull){
  int idx = blockIdx.x*256 + threadIdx.x;          // NH*SEQ*QKH
  int d = idx % QKH; int th = idx / QKH; int t = th & 2047; int hh = th >> 11;
  uint16_t val;
  if (d < DN) {
    val = kvb[(size_t)t*4096 + hh*256 + d];
  } else {
    int dd = d - DN, j = dd >> 1;
    float xr = (float)__builtin_bit_cast(__bf16, kvf[(size_t)t*KVPAD + KVLR + 2*j]);
    float xi = (float)__builtin_bit_cast(__bf16, kvf[(size_t)t*KVPAD + KVLR + 2*j + 1]);
    float c = cs[t*32+j], si = sn[t*32+j];
    val = f2bf((dd & 1) ? (xr*si + xi*c) : (xr*c - xi*si));
  }
  kfull[idx] = val;
}

// v_t[h][d][t] = kvb[t][h*256+128+d]
__global__ void mat_v(const uint16_t* __restrict__ kvb, uint16_t* __restrict__ vtp){
  int idx = blockIdx.x*256 + threadIdx.x;          // NH*DV*SEQ
  int t = idx & 2047, d = (idx>>11) & 127, hh = idx >> 18;
  vtp[idx] = kvb[(size_t)t*4096 + hh*256 + DN + d];
}

// ---------------- attention ----------------
// Barrier-free: each wave owns 16 q-rows; P transpose via per-wave LDS slice.
// Grid: 512 1-D blocks; complementary (qb, 31-qb) pairing so co-resident
// blocks on a CU have balanced causal work.
__device__ __forceinline__ void proc_set(f32x4 s[2], float m[4], float l[4], f32x4 O[8],
                                         uint16_t* pl, int qrow0, int t0, int subrow, int l15)
{
#pragma unroll
  for (int half = 0; half < 2; ++half)
#pragma unroll
    for (int r = 0; r < 4; ++r) {
      float v = s[half][r] * SCALE_F;
      v = fminf(fmaxf(v, -100.f), 100.f);
      if (t0 + half*16 + l15 > qrow0 + subrow + r) v = -1e30f;   // causal
      s[half][r] = v;
    }
  float corr[4];
#pragma unroll
  for (int r = 0; r < 4; ++r) {
    float tm = fmaxf(s[0][r], s[1][r]);
#pragma unroll
    for (int off = 1; off < 16; off <<= 1) tm = fmaxf(tm, __shfl_xor(tm, off, 64));
    float mn = fmaxf(m[r], tm);
    corr[r] = __expf(m[r] - mn);
    m[r] = mn;
  }
#pragma unroll
  for (int r = 0; r < 4; ++r) {
    s[0][r] = __expf(s[0][r] - m[r]);
    s[1][r] = __expf(s[1][r] - m[r]);
    float rs = s[0][r] + s[1][r];
#pragma unroll
    for (int off = 1; off < 16; off <<= 1) rs += __shfl_xor(rs, off, 64);
    l[r] = l[r]*corr[r] + rs;
  }
#pragma unroll
  for (int n = 0; n < 8; ++n)
#pragma unroll
    for (int r = 0; r < 4; ++r) O[n][r] *= corr[r];
#pragma unroll
  for (int half = 0; half < 2; ++half)
#pragma unroll
    for (int r = 0; r < 4; ++r)
      pl[(subrow + r)*PSTR + half*16 + l15] = f2bf(s[half][r]);
}

__global__ __launch_bounds__(256, 2) void attn_kernel(
    const uint16_t* __restrict__ q,     // [SEQ][NH*QKH]
    const uint16_t* __restrict__ kf,    // [NH][SEQ][QKH]
    const uint16_t* __restrict__ vt,    // [NH][DV][SEQ]
    const float* __restrict__ lamp,
    uint16_t* __restrict__ o)           // [SEQ][NH*DV]
{
  __shared__ __align__(16) uint16_t P_lds[4][2][16*PSTR];
  const int b  = blockIdx.x;
  const int h  = b & 15;
  const int j  = (b >> 4) & 15;
  const int qb = (b < 256) ? j : (31 - j);
  const int wid  = threadIdx.x >> 6;
  const int lane = threadIdx.x & 63;
  const int l15 = lane & 15;
  const int lhi = lane >> 4;
  const int subrow = lhi * 4;
  const int qrow0 = qb*64 + wid*16;
  const float lam = lamp[0];

  bf16x8 qf[6];
  {
    const uint16_t* qbase = q + (size_t)(qrow0 + l15)*(NH*QKH) + h*QKH + lhi*8;
#pragma unroll
    for (int kb = 0; kb < 6; ++kb) qf[kb] = ldfrag(qbase + kb*32);
  }
  f32x4 O1[8] = {}, O2[8] = {};
  float m1[4], m2[4], l1[4], l2[4];
#pragma unroll
  for (int r = 0; r < 4; ++r) { m1[r] = m2[r] = -1e30f; l1[r] = l2[r] = 0.f; }

  const uint16_t* kbase = kf + (size_t)h*SEQ*QKH;
  const uint16_t* vbase = vt + (size_t)h*DV*SEQ;
  uint16_t* pl0 = &P_lds[wid][0][0];
  uint16_t* pl1 = &P_lds[wid][1][0];

  for (int t0 = 0; t0 < qrow0 + 16; t0 += 32) {
    // K frags (12) + V frags (8, shared by both sets) — issued up-front;
    // the LDS fence below pins the V loads before the softmax, so their
    // latency hides under ~600cy of VALU.
    bf16x8 kf0[6], kf1[6], vf[8];
    {
      const uint16_t* kp0 = kbase + (size_t)(t0 + l15)*QKH + lhi*8;
      const uint16_t* kp1 = kbase + (size_t)(t0 + 16 + l15)*QKH + lhi*8;
#pragma unroll
      for (int kb = 0; kb < 6; ++kb) { kf0[kb] = ldfrag(kp0 + kb*32); kf1[kb] = ldfrag(kp1 + kb*32); }
#pragma unroll
      for (int n = 0; n < 8; ++n) vf[n] = ldfrag(vbase + (size_t)(n*16 + l15)*SEQ + t0 + lhi*8);
    }
    f32x4 s1[2] = {}, s2[2] = {};
    __builtin_amdgcn_s_setprio(1);
#pragma unroll
    for (int kb = 0; kb < 3; ++kb) { s1[0] = MFMA16(qf[kb], kf0[kb], s1[0]); s1[1] = MFMA16(qf[kb], kf1[kb], s1[1]); }
#pragma unroll
    for (int kb = 3; kb < 6; ++kb) { s2[0] = MFMA16(qf[kb], kf0[kb], s2[0]); s2[1] = MFMA16(qf[kb], kf1[kb], s2[1]); }
    __builtin_amdgcn_s_setprio(0);

    proc_set(s1, m1, l1, O1, pl0, qrow0, t0, subrow, l15);
    proc_set(s2, m2, l2, O2, pl1, qrow0, t0, subrow, l15);

    asm volatile("s_waitcnt lgkmcnt(0)" ::: "memory");
    __builtin_amdgcn_sched_barrier(0);

    bf16x8 pf0 = ldfrag(&pl0[l15*PSTR + lhi*8]);
    bf16x8 pf1 = ldfrag(&pl1[l15*PSTR + lhi*8]);
    __builtin_amdgcn_s_setprio(1);
#pragma unroll
    for (int n = 0; n < 8; ++n) {
      O1[n] = MFMA16(pf0, vf[n], O1[n]);
      O2[n] = MFMA16(pf1, vf[n], O2[n]);
    }
    __builtin_amdgcn_s_setprio(0);
  }
  // epilogue: (O1/l1 - lam*O2/l2) * (1-lambda_init)
#pragma unroll
  for (int r = 0; r < 4; ++r) {
    float inv1 = 1.f / l1[r], inv2 = lam / l2[r];
#pragma unroll
    for (int n = 0; n < 8; ++n) {
      float val = (O1[n][r]*inv1 - O2[n][r]*inv2) * C1F;
      o[(size_t)(qrow0 + subrow + r)*(NH*DV) + h*DV + n*16 + l15] = f2bf(val);
    }
  }
}

// ---------------- launch ----------------
extern "C" void kernel_launch(void* const* d_in, const int* in_sizes, int n_in,
                              void* d_out, int out_size, void* d_ws, size_t ws_size,
                              hipStream_t stream)
{
  const float* x     = (const float*)d_in[0];
  const float* wq_a  = (const float*)d_in[1];
  const float* wq_b  = (const float*)d_in[2];
  const float* wkv_a = (const float*)d_in[3];
  const float* wkv_b = (const float*)d_in[4];
  const float* wo    = (const float*)d_in[5];
  const float* lqn   = (const float*)d_in[6];
  const float* lqr   = (const float*)d_in[7];
  const float* lkn   = (const float*)d_in[8];
  const float* lkr   = (const float*)d_in[9];
  const float* fcos  = (const float*)d_in[10];
  const float* fsin  = (const float*)d_in[11];

  char* ws = (char*)d_ws;
  size_t off = 0;
  float*    lam    = (float*)(ws + off);  off += 256;
  uint16_t* xb     = (uint16_t*)(ws + off); off += (size_t)DIMM*DIMM*2;
  uint16_t* wqab   = (uint16_t*)(ws + off); off += (size_t)QLR*DIMM*2;
  uint16_t* wqbb   = (uint16_t*)(ws + off); off += (size_t)NH*QKH*QLR*2;
  uint16_t* wkvap  = (uint16_t*)(ws + off); off += (size_t)KVPAD*DIMM*2;
  uint16_t* wkvbb  = (uint16_t*)(ws + off); off += (size_t)4096*KVLR*2;
  uint16_t* wob    = (uint16_t*)(ws + off); off += (size_t)DIMM*DIMM*2;
  uint16_t* qlat   = (uint16_t*)(ws + off); off += (size_t)SEQ*QLR*2;
  uint16_t* qbuf   = (uint16_t*)(ws + off); off += (size_t)SEQ*NH*QKH*2;
  uint16_t* kvfull = (uint16_t*)(ws + off); off += (size_t)SEQ*KVPAD*2;
  uint16_t* kvb    = (uint16_t*)(ws + off); off += (size_t)SEQ*4096*2;
  uint16_t* kfull  = (uint16_t*)(ws + off); off += (size_t)NH*SEQ*QKH*2;
  uint16_t* vtb    = (uint16_t*)(ws + off); off += (size_t)NH*DV*SEQ*2;
  uint16_t* attn   = (uint16_t*)(ws + off); off += (size_t)SEQ*NH*DV*2;

  lam_kernel<<<1, 64, 0, stream>>>(lqn, lqr, lkn, lkr, lam);
  cvt<<<2048, 256, 0, stream>>>(x, xb);
  cvt<<< 768, 256, 0, stream>>>(wq_a, wqab);
  cvt<<<1152, 256, 0, stream>>>(wq_b, wqbb);
  cvt<<<1024, 256, 0, stream>>>(wkv_b, wkvbb);
  cvt<<<2048, 256, 0, stream>>>(wo, wob);
  pad_wkva<<<5120, 256, 0, stream>>>(wkv_a, wkvap);

  // q_lat = x @ wq_a^T
  gemm_bt<<<dim3(16, 6), 256, 0, stream>>>(xb, DIMM, wqab, qlat, QLR, DIMM);
  // q = q_lat @ wq_b^T
  gemm_bt<<<dim3(16, 24), 256, 0, stream>>>(qlat, QLR, wqbb, qbuf, NH*QKH, QLR);
  rope_q<<<4096, 256, 0, stream>>>(qbuf, fcos, fsin);
  // kv_full = x @ wkv_a_pad^T
  gemm_bt<<<dim3(16, 5), 256, 0, stream>>>(xb, DIMM, wkvap, kvfull, KVPAD, DIMM);
  // kvb = kv @ wkv_b^T   (kv = first 512 cols of kvfull, lda=640)
  gemm_bt<<<dim3(16, 32), 256, 0, stream>>>(kvfull, KVPAD, wkvbb, kvb, 4096, KVLR);
  mat_k<<<24576, 256, 0, stream>>>(kvb, kvfull, fcos, fsin, kfull);
  mat_v<<<16384, 256, 0, stream>>>(kvb, vtb);
  attn_kernel<<<512, 256, 0, stream>>>(qbuf, kfull, vtb, lam, attn);
  // out = attn_out @ wo^T  (f32 output)
  gemm_bt<<<dim3(16, 16), 256, 0, stream>>>(attn, NH*DV, wob, (float*)d_out, DIMM, DIMM);
}